// Round 2
// baseline (677.064 us; speedup 1.0000x reference)
//
#include <hip/hip_runtime.h>

typedef unsigned short ushort_t;
typedef __attribute__((ext_vector_type(8))) short short8;
typedef __attribute__((ext_vector_type(4))) float f32x4;

// Problem constants (fixed by the reference)
constexpr int N_ATOMS = 50000;
constexpr int N_EDGES = 800000;
constexpr int ELEM    = 64;
constexpr int D_IN    = 192;   // 2*ELEM + NBR
constexpr int D_OUT   = 128;   // 2*ELEM
constexpr float EPS   = 1e-5f;

constexpr int NREP   = 16;     // stat-accumulator replicas

// Edge-group geometry for the operand-swapped GEMM passes.
// One MFMA B-operand = 16 edges (N dim = lane&15). A block's 4 waves SHARE one
// edge chunk; wave w covers output-col tiles {w, 4+w} -> together all 128 cols.
constexpr int NGROUPS     = N_EDGES / 16;        // 50000
constexpr int GEMM_BLOCKS = 5000;
constexpr int CHUNK       = NGROUPS / GEMM_BLOCKS;  // 10 groups (160 edges) per block
static_assert(NGROUPS % GEMM_BLOCKS == 0, "even split");

// Workspace layout (bytes), 16B-aligned. Total ~19.3 MB.
constexpr size_t OFF_NS   = 0;                                        // f32 ns[N][64]
constexpr size_t OFF_ABF  = OFF_NS   + (size_t)N_ATOMS * ELEM * 4;    // bf16 atom_bf[N][64]
constexpr size_t OFF_WT   = OFF_ABF  + (size_t)N_ATOMS * ELEM * 2;    // bf16 Wt[128][192]
constexpr size_t OFF_BN1  = OFF_WT   + (size_t)D_OUT * D_IN * 2;      // f32 [NREP][256]
constexpr size_t OFF_SC1  = OFF_BN1  + NREP * 256 * 4;                // f32 [256]
constexpr size_t OFF_BN2  = OFF_SC1  + 256 * 4;                       // f32 [NREP][128]
constexpr size_t OFF_SC2  = OFF_BN2  + NREP * 128 * 4;                // f32 [128]

__device__ __forceinline__ ushort_t f32_to_bf16(float f) {
    unsigned int u = __float_as_uint(f);
    u = (u + 0x7fffu + ((u >> 16) & 1u)) >> 16;   // RNE
    return (ushort_t)u;
}
__device__ __forceinline__ float softplus_f(float x) {
    return fmaxf(x, 0.f) + __logf(1.f + __expf(-fabsf(x)));
}
__device__ __forceinline__ short8 pack8(float4 a, float4 b) {
    short8 r;
    r[0] = (short)f32_to_bf16(a.x); r[1] = (short)f32_to_bf16(a.y);
    r[2] = (short)f32_to_bf16(a.z); r[3] = (short)f32_to_bf16(a.w);
    r[4] = (short)f32_to_bf16(b.x); r[5] = (short)f32_to_bf16(b.y);
    r[6] = (short)f32_to_bf16(b.z); r[7] = (short)f32_to_bf16(b.w);
    return r;
}

// ---- 0: prep + init: atom->bf16, W->Wt (bf16 transposed), zero ns + replicas ----
__global__ void prep_init_kernel(const float* __restrict__ atom, const float* __restrict__ W,
                                 ushort_t* __restrict__ abf, ushort_t* __restrict__ Wt,
                                 float* __restrict__ ns,
                                 float* __restrict__ bn1r, float* __restrict__ bn2r) {
    int i = blockIdx.x * blockDim.x + threadIdx.x;
    if (i < N_ATOMS * ELEM) { abf[i] = f32_to_bf16(atom[i]); ns[i] = 0.f; }
    if (i < D_IN * D_OUT) {
        int k = i >> 7, n = i & 127;                 // coalesced read of W[k][n]
        Wt[n * D_IN + k] = f32_to_bf16(W[i]);
    }
    if (i < NREP * 256) bn1r[i] = 0.f;
    if (i < NREP * 128) bn2r[i] = 0.f;
}

// Per-group B-fragment gather: edge = group*16 + m16, k-slice = quad*8.
// K layout: [self 0..63 | nbr 64..127 | nbr_fea 128..191]
__device__ __forceinline__ void load_bfrags(short8 (&bf)[6],
                                            const ushort_t* __restrict__ abf,
                                            const float* __restrict__ nbrf,
                                            int si, int ni, int e, int quad) {
    bf[0] = *(const short8*)(abf + (size_t)si * 64 +      quad * 8);
    bf[1] = *(const short8*)(abf + (size_t)si * 64 + 32 + quad * 8);
    bf[2] = *(const short8*)(abf + (size_t)ni * 64 +      quad * 8);
    bf[3] = *(const short8*)(abf + (size_t)ni * 64 + 32 + quad * 8);
    const float* pf = nbrf + (size_t)e * 64 + quad * 8;
    float4 a0 = *(const float4*)(pf);
    float4 a1 = *(const float4*)(pf + 4);
    float4 b0 = *(const float4*)(pf + 32);
    float4 b1 = *(const float4*)(pf + 36);
    bf[4] = pack8(a0, a1);
    bf[5] = pack8(b0, b1);
}

// ---- 1: stats pass — operand-swapped GEMM, col sum/sumsq in registers ----
// A-operand = Wt rows (M = out cols), B-operand = edges (N = edge = m16).
// Bias is analytically absorbed by BN1 (shift-invariance) and dropped.
__global__ __launch_bounds__(256) void stats_kernel(
    const ushort_t* __restrict__ abf, const float* __restrict__ nbrf,
    const int* __restrict__ sidx, const int* __restrict__ nidx,
    const ushort_t* __restrict__ Wt, float* __restrict__ bn1r)
{
    const int tid  = threadIdx.x;
    const int wave = tid >> 6, lane = tid & 63;
    const int m16  = lane & 15, quad = lane >> 4;
    const int wid  = blockIdx.x;                  // all 4 waves share this chunk

    // Persistent W fragments: tiles {wave, 4+wave} -> cols [16w,16w+16) / [64+16w,...)
    short8 wfrag[2][6];
    #pragma unroll
    for (int t = 0; t < 2; ++t) {
        const ushort_t* wp = Wt + (size_t)(t * 64 + wave * 16 + m16) * D_IN + quad * 8;
        #pragma unroll
        for (int ks = 0; ks < 6; ++ks) wfrag[t][ks] = *(const short8*)(wp + ks * 32);
    }

    float s[2][4] = {{0.f,0.f,0.f,0.f},{0.f,0.f,0.f,0.f}};
    float q[2][4] = {{0.f,0.f,0.f,0.f},{0.f,0.f,0.f,0.f}};

    const int g0 = wid * CHUNK;
    int e  = g0 * 16 + m16;
    int si = sidx[e], ni = nidx[e];
    for (int g = g0; g < g0 + CHUNK; ++g) {
        // prefetch next group's indices so the idx->gather chain overlaps MFMA
        int e_n  = e + ((g + 1 < g0 + CHUNK) ? 16 : 0);
        int si_n = sidx[e_n], ni_n = nidx[e_n];

        short8 bf[6];
        load_bfrags(bf, abf, nbrf, si, ni, e, quad);

        f32x4 acc0 = {0.f,0.f,0.f,0.f}, acc1 = {0.f,0.f,0.f,0.f};
        #pragma unroll
        for (int ks = 0; ks < 6; ++ks) {
            acc0 = __builtin_amdgcn_mfma_f32_16x16x32_bf16(wfrag[0][ks], bf[ks], acc0, 0, 0, 0);
            acc1 = __builtin_amdgcn_mfma_f32_16x16x32_bf16(wfrag[1][ks], bf[ks], acc1, 0, 0, 0);
        }
        #pragma unroll
        for (int r = 0; r < 4; ++r) {
            float v0 = acc0[r], v1 = acc1[r];
            s[0][r] += v0; q[0][r] += v0 * v0;
            s[1][r] += v1; q[1][r] += v1 * v1;
        }
        e = e_n; si = si_n; ni = ni_n;
    }

    // reduce the 16 edge-slots (m16) within each quad group, one atomic set per col
    float* rep = bn1r + (size_t)(wid & (NREP - 1)) * 256;
    #pragma unroll
    for (int t = 0; t < 2; ++t)
        #pragma unroll
        for (int r = 0; r < 4; ++r) {
            float sv = s[t][r], qv = q[t][r];
            #pragma unroll
            for (int d = 1; d < 16; d <<= 1) {
                sv += __shfl_xor(sv, d);
                qv += __shfl_xor(qv, d);
            }
            if (m16 == 0) {
                int c = t * 64 + wave * 16 + quad * 4 + r;
                atomicAdd(&rep[c], sv);
                atomicAdd(&rep[128 + c], qv);
            }
        }
}

// ---- 2: finalize BN1 -> per-column scale/shift (bias-free: BN absorbs it) ----
__global__ void bn1_finalize(const float* __restrict__ bn1r,
                             const float* __restrict__ g1, const float* __restrict__ b1,
                             float* __restrict__ sc) {
    int c = threadIdx.x;   // 128
    float s = 0.f, q = 0.f;
    #pragma unroll
    for (int r = 0; r < NREP; ++r) { s += bn1r[r * 256 + c]; q += bn1r[r * 256 + 128 + c]; }
    float mean = s * (1.f / N_EDGES);
    float var  = q * (1.f / N_EDGES) - mean * mean;
    float scale = g1[c] * rsqrtf(var + EPS);
    sc[c] = scale;
    sc[128 + c] = b1[c] - mean * scale;   // BN(t + bias) == t*scale + this shift
}

// ---- 3: msg pass — same GEMM, gate in-lane, segmented-scan segment sum ----
// Wave w: filter cols [16w,16w+16) in acc0, core cols [64+16w,...) in acc1:
// the sigmoid(f)*softplus(c) pair lives in one lane. Edge = m16, sorted sidx
// ascends with m16 -> 16-lane segmented shfl_up scan, run-end lanes do atomics.
__global__ __launch_bounds__(256) void msg_kernel(
    const ushort_t* __restrict__ abf, const float* __restrict__ nbrf,
    const int* __restrict__ sidx, const int* __restrict__ nidx,
    const ushort_t* __restrict__ Wt, const float* __restrict__ sc,
    float* __restrict__ ns)
{
    const int tid  = threadIdx.x;
    const int wave = tid >> 6, lane = tid & 63;
    const int m16  = lane & 15, quad = lane >> 4;
    const int wid  = blockIdx.x;                  // all 4 waves share this chunk

    short8 wfrag[2][6];
    #pragma unroll
    for (int t = 0; t < 2; ++t) {
        const ushort_t* wp = Wt + (size_t)(t * 64 + wave * 16 + m16) * D_IN + quad * 8;
        #pragma unroll
        for (int ks = 0; ks < 6; ++ks) wfrag[t][ks] = *(const short8*)(wp + ks * 32);
    }

    // per-lane BN1 affine params for its 4 filter + 4 core cols (fixed all loop)
    float scf[4], shf[4], scc[4], shc[4];
    #pragma unroll
    for (int r = 0; r < 4; ++r) {
        int cf = wave * 16 + quad * 4 + r;
        scf[r] = sc[cf];       shf[r] = sc[128 + cf];
        scc[r] = sc[64 + cf];  shc[r] = sc[192 + cf];
    }

    const int g0 = wid * CHUNK;
    int e  = g0 * 16 + m16;
    int si = sidx[e], ni = nidx[e];
    for (int g = g0; g < g0 + CHUNK; ++g) {
        int e_n  = e + ((g + 1 < g0 + CHUNK) ? 16 : 0);
        int si_n = sidx[e_n], ni_n = nidx[e_n];
        const int a_self = si;   // this lane's segment id (capture before swap)

        short8 bf[6];
        load_bfrags(bf, abf, nbrf, si, ni, e, quad);

        f32x4 acc0 = {0.f,0.f,0.f,0.f}, acc1 = {0.f,0.f,0.f,0.f};
        #pragma unroll
        for (int ks = 0; ks < 6; ++ks) {
            acc0 = __builtin_amdgcn_mfma_f32_16x16x32_bf16(wfrag[0][ks], bf[ks], acc0, 0, 0, 0);
            acc1 = __builtin_amdgcn_mfma_f32_16x16x32_bf16(wfrag[1][ks], bf[ks], acc1, 0, 0, 0);
        }

        float m[4];
        #pragma unroll
        for (int r = 0; r < 4; ++r) {
            float yf = fmaf(acc0[r], scf[r], shf[r]);
            float yc = fmaf(acc1[r], scc[r], shc[r]);
            m[r] = softplus_f(yc) / (1.f + __expf(-yf));
        }

        // segmented inclusive scan over the 16 sorted edges of this group
        int a = a_self;
        #pragma unroll
        for (int d = 1; d < 16; d <<= 1) {
            int   au = __shfl_up(a,    d, 16);
            float u0 = __shfl_up(m[0], d, 16);
            float u1 = __shfl_up(m[1], d, 16);
            float u2 = __shfl_up(m[2], d, 16);
            float u3 = __shfl_up(m[3], d, 16);
            if (m16 >= d && au == a) { m[0] += u0; m[1] += u1; m[2] += u2; m[3] += u3; }
        }
        int an = __shfl_down(a, 1, 16);
        if (m16 == 15 || an != a) {
            float* p = ns + (size_t)a * 64 + wave * 16 + quad * 4;
            atomicAdd(p + 0, m[0]); atomicAdd(p + 1, m[1]);
            atomicAdd(p + 2, m[2]); atomicAdd(p + 3, m[3]);
        }

        e = e_n; si = si_n; ni = ni_n;
    }
}

// ---- 4: BN2 column stats (replicated atomics) ----
__global__ __launch_bounds__(256) void bn2_stats_kernel(
    const float* __restrict__ ns, float* __restrict__ bn2r)
{
    int c = threadIdx.x & 63;
    float s = 0.f, q = 0.f;
    for (int a = blockIdx.x * 4 + (threadIdx.x >> 6); a < N_ATOMS; a += 4096) {
        float v = ns[a * ELEM + c];
        s += v; q += v * v;
    }
    float* rep = bn2r + (size_t)(blockIdx.x & (NREP - 1)) * 128;
    atomicAdd(&rep[c], s);
    atomicAdd(&rep[64 + c], q);
}

// ---- 5: finalize BN2 ----
__global__ void bn2_finalize(const float* __restrict__ bn2r,
                             const float* __restrict__ g2, const float* __restrict__ b2,
                             float* __restrict__ sc2) {
    int c = threadIdx.x;   // 64
    float s = 0.f, q = 0.f;
    #pragma unroll
    for (int r = 0; r < NREP; ++r) { s += bn2r[r * 128 + c]; q += bn2r[r * 128 + 64 + c]; }
    float mean = s * (1.f / N_ATOMS);
    float var  = q * (1.f / N_ATOMS) - mean * mean;
    float scale = g2[c] * rsqrtf(var + EPS);
    sc2[c] = scale;
    sc2[64 + c] = b2[c] - mean * scale;
}

// ---- 6: BN2 affine + residual + softplus ----
__global__ void final_kernel(const float* __restrict__ atom, const float* __restrict__ ns,
                             const float* __restrict__ sc2, float* __restrict__ out)
{
    int i = blockIdx.x * blockDim.x + threadIdx.x;
    if (i < N_ATOMS * ELEM) {
        int c = i & 63;
        float x = atom[i] + fmaf(ns[i], sc2[c], sc2[64 + c]);
        out[i] = softplus_f(x);
    }
}

extern "C" void kernel_launch(void* const* d_in, const int* in_sizes, int n_in,
                              void* d_out, int out_size, void* d_ws, size_t ws_size,
                              hipStream_t stream) {
    const float* atom = (const float*)d_in[0];
    const float* nbrf = (const float*)d_in[1];
    const int*   sidx = (const int*)d_in[2];
    const int*   nidx = (const int*)d_in[3];
    const float* W    = (const float*)d_in[4];
    // d_in[5] (bias) is analytically absorbed by BN1 and unused on-device.
    const float* g1   = (const float*)d_in[6];
    const float* b1   = (const float*)d_in[7];
    const float* g2   = (const float*)d_in[8];
    const float* b2   = (const float*)d_in[9];
    float* out = (float*)d_out;
    char*  ws  = (char*)d_ws;

    float*    ns   = (float*)(ws + OFF_NS);
    ushort_t* abf  = (ushort_t*)(ws + OFF_ABF);
    ushort_t* Wt   = (ushort_t*)(ws + OFF_WT);
    float*    bn1r = (float*)(ws + OFF_BN1);
    float*    sc1  = (float*)(ws + OFF_SC1);
    float*    bn2r = (float*)(ws + OFF_BN2);
    float*    sc2  = (float*)(ws + OFF_SC2);

    hipLaunchKernelGGL(prep_init_kernel, dim3((N_ATOMS * ELEM + 255) / 256), dim3(256), 0, stream,
                       atom, W, abf, Wt, ns, bn1r, bn2r);
    hipLaunchKernelGGL(stats_kernel, dim3(GEMM_BLOCKS), dim3(256), 0, stream,
                       abf, nbrf, sidx, nidx, Wt, bn1r);
    hipLaunchKernelGGL(bn1_finalize, dim3(1), dim3(128), 0, stream, bn1r, g1, b1, sc1);
    hipLaunchKernelGGL(msg_kernel, dim3(GEMM_BLOCKS), dim3(256), 0, stream,
                       abf, nbrf, sidx, nidx, Wt, sc1, ns);
    hipLaunchKernelGGL(bn2_stats_kernel, dim3(1024), dim3(256), 0, stream, ns, bn2r);
    hipLaunchKernelGGL(bn2_finalize, dim3(1), dim3(64), 0, stream, bn2r, g2, b2, sc2);
    hipLaunchKernelGGL(final_kernel, dim3((N_ATOMS * ELEM + 255) / 256), dim3(256), 0, stream,
                       atom, ns, sc2, out);
}

// Round 3
// 486.338 us; speedup vs baseline: 1.3922x; 1.3922x over previous
//
#include <hip/hip_runtime.h>

typedef unsigned short ushort_t;
typedef __attribute__((ext_vector_type(8))) short short8;
typedef __attribute__((ext_vector_type(4))) float f32x4;

// Problem constants (fixed by the reference)
constexpr int N_ATOMS = 50000;
constexpr int N_EDGES = 800000;
constexpr int ELEM    = 64;
constexpr int D_IN    = 192;   // 2*ELEM + NBR
constexpr int D_OUT   = 128;   // 2*ELEM
constexpr float EPS   = 1e-5f;

constexpr int NREP   = 16;     // stat-accumulator replicas

// GEMM geometry: 64-edge LDS tile per block-iteration (4 groups of 16 edges).
// 4 waves/block; wave w covers output-col tiles {w, 4+w} -> all 128 cols/block.
constexpr int EDGE_TILE       = 64;
constexpr int TILES_PER_BLOCK = 5;
constexpr int GEMM_BLOCKS     = N_EDGES / (EDGE_TILE * TILES_PER_BLOCK);  // 2500
static_assert(N_EDGES % (EDGE_TILE * TILES_PER_BLOCK) == 0, "even split");

// Workspace layout (bytes), 16B-aligned. Total ~19.3 MB.
constexpr size_t OFF_NS   = 0;                                        // f32 ns[N][64]
constexpr size_t OFF_ABF  = OFF_NS   + (size_t)N_ATOMS * ELEM * 4;    // bf16 atom_bf[N][64]
constexpr size_t OFF_WT   = OFF_ABF  + (size_t)N_ATOMS * ELEM * 2;    // bf16 Wt[128][192]
constexpr size_t OFF_BN1  = OFF_WT   + (size_t)D_OUT * D_IN * 2;      // f32 [NREP][256]
constexpr size_t OFF_SC1  = OFF_BN1  + NREP * 256 * 4;                // f32 [256]
constexpr size_t OFF_BN2  = OFF_SC1  + 256 * 4;                       // f32 [NREP][128]
constexpr size_t OFF_SC2  = OFF_BN2  + NREP * 128 * 4;                // f32 [128]

__device__ __forceinline__ ushort_t f32_to_bf16(float f) {
    unsigned int u = __float_as_uint(f);
    u = (u + 0x7fffu + ((u >> 16) & 1u)) >> 16;   // RNE
    return (ushort_t)u;
}
__device__ __forceinline__ float softplus_f(float x) {
    return fmaxf(x, 0.f) + __logf(1.f + __expf(-fabsf(x)));
}
__device__ __forceinline__ short8 pack8(float4 a, float4 b) {
    short8 r;
    r[0] = (short)f32_to_bf16(a.x); r[1] = (short)f32_to_bf16(a.y);
    r[2] = (short)f32_to_bf16(a.z); r[3] = (short)f32_to_bf16(a.w);
    r[4] = (short)f32_to_bf16(b.x); r[5] = (short)f32_to_bf16(b.y);
    r[6] = (short)f32_to_bf16(b.z); r[7] = (short)f32_to_bf16(b.w);
    return r;
}

// ---- 0: prep + init: atom->bf16, W->Wt (bf16 transposed), zero ns + replicas ----
__global__ void prep_init_kernel(const float* __restrict__ atom, const float* __restrict__ W,
                                 ushort_t* __restrict__ abf, ushort_t* __restrict__ Wt,
                                 float* __restrict__ ns,
                                 float* __restrict__ bn1r, float* __restrict__ bn2r) {
    int i = blockIdx.x * blockDim.x + threadIdx.x;
    if (i < N_ATOMS * ELEM) { abf[i] = f32_to_bf16(atom[i]); ns[i] = 0.f; }
    if (i < D_IN * D_OUT) {
        int k = i >> 7, n = i & 127;                 // coalesced read of W[k][n]
        Wt[n * D_IN + k] = f32_to_bf16(W[i]);
    }
    if (i < NREP * 256) bn1r[i] = 0.f;
    if (i < NREP * 128) bn2r[i] = 0.f;
}

// LDS B-fragment tile: Bs unit = 16B (8 ushorts), addr (gg,ks,m16,quad) =
// ((gg*6+ks)*64 + m16*4 + quad)*8 ushorts.  4 groups x 6 ks x 1KB = 24 KB.
// K layout: ks 0..1 = self row, 2..3 = nbr row, 4..5 = nbr_fea (bf16-packed).
constexpr int BS_USHORTS = 4 * 6 * 64 * 8;   // 12288 -> 24 KB

__device__ __forceinline__ void stage_tile(ushort_t* __restrict__ Bs,
                                           const ushort_t* __restrict__ abf,
                                           const float* __restrict__ nbrf,
                                           const int* __restrict__ sidx,
                                           const int* __restrict__ nidx,
                                           int e0, int tid) {
    // 512 16B-chunks per source; thread handles chunks {tid, tid+256}.
    // chunk c: edge e = c>>3 (tile-local), h = c&7 -> ks_sub = h>>2, quad = h&3,
    // covering elements [h*8, h*8+8) of that edge's row.
    #pragma unroll
    for (int half = 0; half < 2; ++half) {
        int c = tid + half * 256;
        int e = c >> 3, h = c & 7;
        int gg = e >> 4, m16 = e & 15;
        int kss = h >> 2, quad = h & 3;
        int rs = sidx[e0 + e];                 // 8 threads/edge -> broadcast-merged
        int rn = nidx[e0 + e];
        uint4 vs = *(const uint4*)(abf + (size_t)rs * 64 + h * 8);
        uint4 vn = *(const uint4*)(abf + (size_t)rn * 64 + h * 8);
        const float* pf = nbrf + (size_t)(e0 + e) * 64 + h * 8;
        float4 fa = *(const float4*)pf;
        float4 fb = *(const float4*)(pf + 4);
        *(uint4*)&Bs[((gg * 6 + 0 + kss) * 64 + m16 * 4 + quad) * 8] = vs;
        *(uint4*)&Bs[((gg * 6 + 2 + kss) * 64 + m16 * 4 + quad) * 8] = vn;
        short8 pk = pack8(fa, fb);
        *(short8*)&Bs[((gg * 6 + 4 + kss) * 64 + m16 * 4 + quad) * 8] = pk;
    }
}

// ---- 1: stats pass — LDS-shared B-fragments, operand-swapped GEMM ----
// A-operand = Wt rows (M = out cols), B-operand = edges (N = edge = m16).
// Bias is analytically absorbed by BN1 (shift-invariance) and dropped.
__global__ __launch_bounds__(256) void stats_kernel(
    const ushort_t* __restrict__ abf, const float* __restrict__ nbrf,
    const int* __restrict__ sidx, const int* __restrict__ nidx,
    const ushort_t* __restrict__ Wt, float* __restrict__ bn1r)
{
    __shared__ __align__(16) ushort_t Bs[BS_USHORTS];
    const int tid  = threadIdx.x;
    const int wave = tid >> 6, lane = tid & 63;
    const int m16  = lane & 15, quad = lane >> 4;

    // Persistent W fragments: tiles {wave, 4+wave} -> cols [16w,16w+16) / [64+16w,...)
    short8 wfrag[2][6];
    #pragma unroll
    for (int t = 0; t < 2; ++t) {
        const ushort_t* wp = Wt + (size_t)(t * 64 + wave * 16 + m16) * D_IN + quad * 8;
        #pragma unroll
        for (int ks = 0; ks < 6; ++ks) wfrag[t][ks] = *(const short8*)(wp + ks * 32);
    }

    float s[2][4] = {{0.f,0.f,0.f,0.f},{0.f,0.f,0.f,0.f}};
    float q[2][4] = {{0.f,0.f,0.f,0.f},{0.f,0.f,0.f,0.f}};

    for (int t = 0; t < TILES_PER_BLOCK; ++t) {
        const int e0 = (blockIdx.x * TILES_PER_BLOCK + t) * EDGE_TILE;
        stage_tile(Bs, abf, nbrf, sidx, nidx, e0, tid);
        __syncthreads();

        #pragma unroll
        for (int gg = 0; gg < 4; ++gg) {
            short8 bf[6];
            #pragma unroll
            for (int ks = 0; ks < 6; ++ks)
                bf[ks] = *(const short8*)&Bs[((gg * 6 + ks) * 64 + m16 * 4 + quad) * 8];

            f32x4 acc0 = {0.f,0.f,0.f,0.f}, acc1 = {0.f,0.f,0.f,0.f};
            #pragma unroll
            for (int ks = 0; ks < 6; ++ks) {
                acc0 = __builtin_amdgcn_mfma_f32_16x16x32_bf16(wfrag[0][ks], bf[ks], acc0, 0, 0, 0);
                acc1 = __builtin_amdgcn_mfma_f32_16x16x32_bf16(wfrag[1][ks], bf[ks], acc1, 0, 0, 0);
            }
            #pragma unroll
            for (int r = 0; r < 4; ++r) {
                float v0 = acc0[r], v1 = acc1[r];
                s[0][r] += v0; q[0][r] += v0 * v0;
                s[1][r] += v1; q[1][r] += v1 * v1;
            }
        }
        __syncthreads();   // reads done before next tile's stage overwrites
    }

    // reduce the 16 edge-slots (m16) within each quad group, one atomic set per col
    float* rep = bn1r + (size_t)(blockIdx.x & (NREP - 1)) * 256;
    #pragma unroll
    for (int t = 0; t < 2; ++t)
        #pragma unroll
        for (int r = 0; r < 4; ++r) {
            float sv = s[t][r], qv = q[t][r];
            #pragma unroll
            for (int d = 1; d < 16; d <<= 1) {
                sv += __shfl_xor(sv, d);
                qv += __shfl_xor(qv, d);
            }
            if (m16 == 0) {
                int c = t * 64 + wave * 16 + quad * 4 + r;
                atomicAdd(&rep[c], sv);
                atomicAdd(&rep[128 + c], qv);
            }
        }
}

// ---- 2: finalize BN1 -> per-column scale/shift (bias-free: BN absorbs it) ----
__global__ void bn1_finalize(const float* __restrict__ bn1r,
                             const float* __restrict__ g1, const float* __restrict__ b1,
                             float* __restrict__ sc) {
    int c = threadIdx.x;   // 128
    float s = 0.f, q = 0.f;
    #pragma unroll
    for (int r = 0; r < NREP; ++r) { s += bn1r[r * 256 + c]; q += bn1r[r * 256 + 128 + c]; }
    float mean = s * (1.f / N_EDGES);
    float var  = q * (1.f / N_EDGES) - mean * mean;
    float scale = g1[c] * rsqrtf(var + EPS);
    sc[c] = scale;
    sc[128 + c] = b1[c] - mean * scale;   // BN(t + bias) == t*scale + this shift
}

// ---- 3: msg pass — same GEMM, gate in-lane, segmented-scan segment sum ----
// Wave w: filter cols [16w,16w+16) in acc0, core cols [64+16w,...) in acc1:
// the sigmoid(f)*softplus(c) pair lives in one lane. Edge = m16, sorted sidx
// ascends with m16 -> 16-lane segmented shfl_up scan, run-end lanes do atomics.
__global__ __launch_bounds__(256) void msg_kernel(
    const ushort_t* __restrict__ abf, const float* __restrict__ nbrf,
    const int* __restrict__ sidx, const int* __restrict__ nidx,
    const ushort_t* __restrict__ Wt, const float* __restrict__ sc,
    float* __restrict__ ns)
{
    __shared__ __align__(16) ushort_t Bs[BS_USHORTS];
    __shared__ int ss[EDGE_TILE];
    const int tid  = threadIdx.x;
    const int wave = tid >> 6, lane = tid & 63;
    const int m16  = lane & 15, quad = lane >> 4;

    short8 wfrag[2][6];
    #pragma unroll
    for (int t = 0; t < 2; ++t) {
        const ushort_t* wp = Wt + (size_t)(t * 64 + wave * 16 + m16) * D_IN + quad * 8;
        #pragma unroll
        for (int ks = 0; ks < 6; ++ks) wfrag[t][ks] = *(const short8*)(wp + ks * 32);
    }

    // per-lane BN1 affine params for its 4 filter + 4 core cols (fixed all loop)
    float scf[4], shf[4], scc[4], shc[4];
    #pragma unroll
    for (int r = 0; r < 4; ++r) {
        int cf = wave * 16 + quad * 4 + r;
        scf[r] = sc[cf];       shf[r] = sc[128 + cf];
        scc[r] = sc[64 + cf];  shc[r] = sc[192 + cf];
    }

    for (int t = 0; t < TILES_PER_BLOCK; ++t) {
        const int e0 = (blockIdx.x * TILES_PER_BLOCK + t) * EDGE_TILE;
        stage_tile(Bs, abf, nbrf, sidx, nidx, e0, tid);
        if (tid < EDGE_TILE) ss[tid] = sidx[e0 + tid];
        __syncthreads();

        #pragma unroll
        for (int gg = 0; gg < 4; ++gg) {
            short8 bf[6];
            #pragma unroll
            for (int ks = 0; ks < 6; ++ks)
                bf[ks] = *(const short8*)&Bs[((gg * 6 + ks) * 64 + m16 * 4 + quad) * 8];

            f32x4 acc0 = {0.f,0.f,0.f,0.f}, acc1 = {0.f,0.f,0.f,0.f};
            #pragma unroll
            for (int ks = 0; ks < 6; ++ks) {
                acc0 = __builtin_amdgcn_mfma_f32_16x16x32_bf16(wfrag[0][ks], bf[ks], acc0, 0, 0, 0);
                acc1 = __builtin_amdgcn_mfma_f32_16x16x32_bf16(wfrag[1][ks], bf[ks], acc1, 0, 0, 0);
            }

            float m[4];
            #pragma unroll
            for (int r = 0; r < 4; ++r) {
                float yf = fmaf(acc0[r], scf[r], shf[r]);
                float yc = fmaf(acc1[r], scc[r], shc[r]);
                m[r] = softplus_f(yc) / (1.f + __expf(-yf));
            }

            // segmented inclusive scan over the 16 sorted edges of this group
            int a = ss[gg * 16 + m16];
            #pragma unroll
            for (int d = 1; d < 16; d <<= 1) {
                int   au = __shfl_up(a,    d, 16);
                float u0 = __shfl_up(m[0], d, 16);
                float u1 = __shfl_up(m[1], d, 16);
                float u2 = __shfl_up(m[2], d, 16);
                float u3 = __shfl_up(m[3], d, 16);
                if (m16 >= d && au == a) { m[0] += u0; m[1] += u1; m[2] += u2; m[3] += u3; }
            }
            int an = __shfl_down(a, 1, 16);
            if (m16 == 15 || an != a) {
                float* p = ns + (size_t)a * 64 + wave * 16 + quad * 4;
                atomicAdd(p + 0, m[0]); atomicAdd(p + 1, m[1]);
                atomicAdd(p + 2, m[2]); atomicAdd(p + 3, m[3]);
            }
        }
        __syncthreads();   // reads done before next tile's stage overwrites
    }
}

// ---- 4: BN2 column stats (replicated atomics) ----
__global__ __launch_bounds__(256) void bn2_stats_kernel(
    const float* __restrict__ ns, float* __restrict__ bn2r)
{
    int c = threadIdx.x & 63;
    float s = 0.f, q = 0.f;
    for (int a = blockIdx.x * 4 + (threadIdx.x >> 6); a < N_ATOMS; a += 4096) {
        float v = ns[a * ELEM + c];
        s += v; q += v * v;
    }
    float* rep = bn2r + (size_t)(blockIdx.x & (NREP - 1)) * 128;
    atomicAdd(&rep[c], s);
    atomicAdd(&rep[64 + c], q);
}

// ---- 5: finalize BN2 ----
__global__ void bn2_finalize(const float* __restrict__ bn2r,
                             const float* __restrict__ g2, const float* __restrict__ b2,
                             float* __restrict__ sc2) {
    int c = threadIdx.x;   // 64
    float s = 0.f, q = 0.f;
    #pragma unroll
    for (int r = 0; r < NREP; ++r) { s += bn2r[r * 128 + c]; q += bn2r[r * 128 + 64 + c]; }
    float mean = s * (1.f / N_ATOMS);
    float var  = q * (1.f / N_ATOMS) - mean * mean;
    float scale = g2[c] * rsqrtf(var + EPS);
    sc2[c] = scale;
    sc2[64 + c] = b2[c] - mean * scale;
}

// ---- 6: BN2 affine + residual + softplus ----
__global__ void final_kernel(const float* __restrict__ atom, const float* __restrict__ ns,
                             const float* __restrict__ sc2, float* __restrict__ out)
{
    int i = blockIdx.x * blockDim.x + threadIdx.x;
    if (i < N_ATOMS * ELEM) {
        int c = i & 63;
        float x = atom[i] + fmaf(ns[i], sc2[c], sc2[64 + c]);
        out[i] = softplus_f(x);
    }
}

extern "C" void kernel_launch(void* const* d_in, const int* in_sizes, int n_in,
                              void* d_out, int out_size, void* d_ws, size_t ws_size,
                              hipStream_t stream) {
    const float* atom = (const float*)d_in[0];
    const float* nbrf = (const float*)d_in[1];
    const int*   sidx = (const int*)d_in[2];
    const int*   nidx = (const int*)d_in[3];
    const float* W    = (const float*)d_in[4];
    // d_in[5] (bias) is analytically absorbed by BN1 and unused on-device.
    const float* g1   = (const float*)d_in[6];
    const float* b1   = (const float*)d_in[7];
    const float* g2   = (const float*)d_in[8];
    const float* b2   = (const float*)d_in[9];
    float* out = (float*)d_out;
    char*  ws  = (char*)d_ws;

    float*    ns   = (float*)(ws + OFF_NS);
    ushort_t* abf  = (ushort_t*)(ws + OFF_ABF);
    ushort_t* Wt   = (ushort_t*)(ws + OFF_WT);
    float*    bn1r = (float*)(ws + OFF_BN1);
    float*    sc1  = (float*)(ws + OFF_SC1);
    float*    bn2r = (float*)(ws + OFF_BN2);
    float*    sc2  = (float*)(ws + OFF_SC2);

    hipLaunchKernelGGL(prep_init_kernel, dim3((N_ATOMS * ELEM + 255) / 256), dim3(256), 0, stream,
                       atom, W, abf, Wt, ns, bn1r, bn2r);
    hipLaunchKernelGGL(stats_kernel, dim3(GEMM_BLOCKS), dim3(256), 0, stream,
                       abf, nbrf, sidx, nidx, Wt, bn1r);
    hipLaunchKernelGGL(bn1_finalize, dim3(1), dim3(128), 0, stream, bn1r, g1, b1, sc1);
    hipLaunchKernelGGL(msg_kernel, dim3(GEMM_BLOCKS), dim3(256), 0, stream,
                       abf, nbrf, sidx, nidx, Wt, sc1, ns);
    hipLaunchKernelGGL(bn2_stats_kernel, dim3(1024), dim3(256), 0, stream, ns, bn2r);
    hipLaunchKernelGGL(bn2_finalize, dim3(1), dim3(64), 0, stream, bn2r, g2, b2, sc2);
    hipLaunchKernelGGL(final_kernel, dim3((N_ATOMS * ELEM + 255) / 256), dim3(256), 0, stream,
                       atom, ns, sc2, out);
}